// Round 5
// baseline (3315.894 us; speedup 1.0000x reference)
//
#include <hip/hip_runtime.h>

#define KDIM 128

// ---------------------------------------------------------------------------
// CSR build: histogram of src, exclusive scan, scatter (dst -> col), row sort
// ---------------------------------------------------------------------------
__global__ void hist_kernel(const int* __restrict__ src, int* __restrict__ cnt, int E) {
    int i = blockIdx.x * blockDim.x + threadIdx.x;
    if (i < E) atomicAdd(&cnt[src[i]], 1);
}

__global__ void scan_kernel(const int* __restrict__ cnt, int* __restrict__ row_ptr,
                            int* __restrict__ cursor, int N) {
    __shared__ int wsum[16];
    __shared__ int base_sh;
    const int tid = threadIdx.x;
    const int lane = tid & 63;
    const int w = tid >> 6;
    if (tid == 0) base_sh = 0;
    __syncthreads();
    for (int base = 0; base < N; base += 1024) {
        int i = base + tid;
        int v = (i < N) ? cnt[i] : 0;
        int x = v;
        #pragma unroll
        for (int off = 1; off < 64; off <<= 1) {
            int t = __shfl_up(x, off);
            if (lane >= off) x += t;
        }
        if (lane == 63) wsum[w] = x;
        __syncthreads();
        if (tid < 16) {
            int t = wsum[tid];
            #pragma unroll
            for (int off = 1; off < 16; off <<= 1) {
                int u = __shfl_up(t, off);
                if (tid >= off) t += u;
            }
            wsum[tid] = t;  // inclusive over waves
        }
        __syncthreads();
        int wexcl = (w == 0) ? 0 : wsum[w - 1];
        int excl = base_sh + wexcl + (x - v);
        if (i < N) { row_ptr[i] = excl; cursor[i] = excl; }
        int total = wsum[15];
        __syncthreads();
        if (tid == 0) base_sh += total;
        __syncthreads();
    }
    if (threadIdx.x == 0) row_ptr[N] = base_sh;
}

__global__ void scatter_kernel(const int* __restrict__ src, const int* __restrict__ dst,
                               int* cursor, int* __restrict__ col, int E) {
    int i = blockIdx.x * blockDim.x + threadIdx.x;
    if (i < E) {
        int p = atomicAdd(&cursor[src[i]], 1);
        col[p] = dst[i];
    }
}

// Sort each CSR row's col values ascending -> deterministic summation order.
__global__ void sortrows_kernel(const int* __restrict__ row_ptr, int* __restrict__ col, int M) {
    int wid = (blockIdx.x * blockDim.x + threadIdx.x) >> 6;
    int lane = threadIdx.x & 63;
    if (wid >= M) return;
    int s = row_ptr[wid], e = row_ptr[wid + 1], len = e - s;
    if (len <= 1) return;
    if (len <= 64) {
        int v = (lane < len) ? col[s + lane] : 0x7fffffff;
        #pragma unroll
        for (int k = 2; k <= 64; k <<= 1) {
            #pragma unroll
            for (int j = k >> 1; j > 0; j >>= 1) {
                int o = __shfl_xor(v, j);
                bool dir = ((lane & k) == 0);      // ascending block?
                bool smaller = ((lane & j) == 0);  // lower partner?
                int mn = min(v, o), mx = max(v, o);
                v = (dir == smaller) ? mn : mx;
            }
        }
        if (lane < len) col[s + lane] = v;
    } else if (lane == 0) {
        // rare fallback (deg > 64): insertion sort in global memory
        for (int a = s + 1; a < e; a++) {
            int key = col[a];
            int b = a - 1;
            while (b >= s && col[b] > key) { col[b + 1] = col[b]; b--; }
            col[b + 1] = key;
        }
    }
}

// ---------------------------------------------------------------------------
// MaxK: keep top-32 of 128 per row (jax.lax.top_k tie-break: lower index wins)
// One wave per row; ballot+popcount radix select (no cross-lane data moves).
// ---------------------------------------------------------------------------
__global__ void maxk_kernel(const float* __restrict__ h, float* __restrict__ hs, int M) {
    int wid = (blockIdx.x * blockDim.x + threadIdx.x) >> 6;
    int lane = threadIdx.x & 63;
    if (wid >= M) return;
    float2 v = ((const float2*)(h + (size_t)wid * KDIM))[lane];

    // orderable keys: larger float <-> larger uint
    unsigned int u0 = __float_as_uint(v.x);
    u0 = (u0 & 0x80000000u) ? ~u0 : (u0 | 0x80000000u);
    unsigned int u1 = __float_as_uint(v.y);
    u1 = (u1 & 0x80000000u) ? ~u1 : (u1 | 0x80000000u);

    // MSB radix select: find T = key of the 32nd largest element
    unsigned int prefix = 0;
    int remaining = 32;
    #pragma unroll
    for (int b = 31; b >= 0; --b) {
        unsigned int candHi = (prefix >> b) | 1u;  // high bits (31..b) of candidate
        unsigned long long m0 = __ballot((u0 >> b) == candHi);
        unsigned long long m1 = __ballot((u1 >> b) == candHi);
        int cnt = __popcll(m0) + __popcll(m1);
        if (cnt >= remaining) prefix |= (1u << b);
        else remaining -= cnt;
    }

    // keep all keys > T; among == T keep lowest element indices (idx = 2*lane+j)
    unsigned long long e0 = __ballot(u0 == prefix);
    unsigned long long e1 = __ballot(u1 == prefix);
    unsigned long long g0 = __ballot(u0 > prefix);
    unsigned long long g1 = __ballot(u1 > prefix);
    int quota = 32 - (__popcll(g0) + __popcll(g1));  // how many ==T to keep
    unsigned long long below = (1ULL << lane) - 1ULL;
    int rank0 = __popcll(e0 & below) + __popcll(e1 & below);
    int rank1 = rank0 + (int)((e0 >> lane) & 1ULL);
    bool k0 = (u0 > prefix) || (((e0 >> lane) & 1ULL) && rank0 < quota);
    bool k1 = (u1 > prefix) || (((e1 >> lane) & 1ULL) && rank1 < quota);

    float2 o;
    o.x = k0 ? v.x : 0.0f;
    o.y = k1 ? v.y : 0.0f;
    ((float2*)(hs + (size_t)wid * KDIM))[lane] = o;
}

// ---------------------------------------------------------------------------
// Aggregation: agg[s] = (sum over CSR row s of hs[col]) / (deg + 1e-6)
// One wave per node. 2 half-waves x 4-chain unroll = up to 8 independent
// 512B float4 row loads in flight per wave (latency hiding via MLP).
// Deterministic fixed combine order: chains 0..3, then half0 + half1.
// ---------------------------------------------------------------------------
__global__ __launch_bounds__(256)
void aggregate_kernel(const float* __restrict__ hs, const int* __restrict__ row_ptr,
                      const int* __restrict__ col, float* __restrict__ agg, int M) {
    const int lane = threadIdx.x & 63;
    const int wid = (blockIdx.x * blockDim.x + threadIdx.x) >> 6;
    if (wid >= M) return;
    const int half = lane >> 5;
    const int l32 = lane & 31;
    const int s = row_ptr[wid], e = row_ptr[wid + 1];
    const float4* __restrict__ hp = (const float4*)hs;  // row c -> hp[c*32 + l32]

    float4 a0 = make_float4(0.f, 0.f, 0.f, 0.f);
    float4 a1 = a0, a2 = a0, a3 = a0;

    int j = s + half;  // this half handles edges (j - s) even/odd per half
    for (; j + 6 < e; j += 8) {
        int c0 = col[j];
        int c1 = col[j + 2];
        int c2 = col[j + 4];
        int c3 = col[j + 6];
        float4 v0 = hp[(size_t)c0 * 32 + l32];
        float4 v1 = hp[(size_t)c1 * 32 + l32];
        float4 v2 = hp[(size_t)c2 * 32 + l32];
        float4 v3 = hp[(size_t)c3 * 32 + l32];
        a0.x += v0.x; a0.y += v0.y; a0.z += v0.z; a0.w += v0.w;
        a1.x += v1.x; a1.y += v1.y; a1.z += v1.z; a1.w += v1.w;
        a2.x += v2.x; a2.y += v2.y; a2.z += v2.z; a2.w += v2.w;
        a3.x += v3.x; a3.y += v3.y; a3.z += v3.z; a3.w += v3.w;
    }
    for (; j < e; j += 2) {  // tail for this half (deterministic: into a0)
        int c = col[j];
        float4 v = hp[(size_t)c * 32 + l32];
        a0.x += v.x; a0.y += v.y; a0.z += v.z; a0.w += v.w;
    }

    // combine chains in fixed order: ((a0 + a1) + a2) + a3
    float4 t;
    t.x = ((a0.x + a1.x) + a2.x) + a3.x;
    t.y = ((a0.y + a1.y) + a2.y) + a3.y;
    t.z = ((a0.z + a1.z) + a2.z) + a3.z;
    t.w = ((a0.w + a1.w) + a2.w) + a3.w;

    // cross-half combine: lane<32 gets half0 + half1 (fixed order)
    float4 u;
    u.x = __shfl_xor(t.x, 32);
    u.y = __shfl_xor(t.y, 32);
    u.z = __shfl_xor(t.z, 32);
    u.w = __shfl_xor(t.w, 32);

    if (half == 0) {
        float inv = 1.0f / ((float)(e - s) + 1e-6f);
        float4 o;
        o.x = (t.x + u.x) * inv;
        o.y = (t.y + u.y) * inv;
        o.z = (t.z + u.z) * inv;
        o.w = (t.w + u.w) * inv;
        ((float4*)(agg + (size_t)wid * KDIM))[l32] = o;
    }
}

// ---------------------------------------------------------------------------
// f32 GEMM: C[M,BN] = A1[M,128] @ B1[128,BN] (+ A2 @ B2) (+ bias)
// BM=64 tile (grid 782 -> ~3 blocks/CU for occupancy), 256 threads,
// acc 4 rows x (BN/16) cols per thread. Two-barrier register double-buffer:
// prefetch chunk c+2 into regs while computing chunk c from LDS.
// ---------------------------------------------------------------------------
template <int BN, bool DUAL, bool BIAS>
__global__ __launch_bounds__(256, 4)
void gemm_f32(const float* __restrict__ A1, const float* __restrict__ B1,
              const float* __restrict__ A2, const float* __restrict__ B2,
              const float* __restrict__ bias, float* __restrict__ C, int M) {
    constexpr int BM = 64;
    constexpr int KC = 32;
    constexpr int BMP = BM + 4;            // 68: A-read banks 2-way, 16B-aligned
    constexpr int BNP = BN + 4;            // 132/68
    constexpr int NCH = (DUAL ? 8 : 4);    // (src,kc) chunks
    constexpr int CPT = BN / 16;           // cols per thread: 8 or 4
    constexpr int AREG = (BM * KC / 4) / 256;   // 2 float4
    constexpr int BREG = (KC * BN / 4) / 256;   // 4 or 2 float4

    __shared__ float As[KC][BMP];   // transposed: As[k][m]
    __shared__ float Bs[KC][BNP];

    const int tid = threadIdx.x;
    const int tx = tid & 15;        // 16 col-groups
    const int ty = tid >> 4;        // 16 row-groups x 4 rows
    const int row0 = blockIdx.x * BM;

    float4 pa[AREG], pb[BREG];

    auto loadA = [&](int c, float4* r) {
        const float* A = (DUAL && c >= 4) ? A2 : A1;
        const int kc = (c & 3) * KC;
        #pragma unroll
        for (int q = 0; q < AREG; q++) {
            int idx = tid + q * 256;
            int m = idx >> 3, kq = idx & 7;   // 8 lanes per row: 128B coalesced
            int row = row0 + m;
            r[q] = (row < M) ? *(const float4*)(A + (size_t)row * KDIM + kc + kq * 4)
                             : make_float4(0.f, 0.f, 0.f, 0.f);
        }
    };
    auto loadB = [&](int c, float4* r) {
        const float* B = (DUAL && c >= 4) ? B2 : B1;
        const int kc = (c & 3) * KC;
        #pragma unroll
        for (int q = 0; q < BREG; q++) {
            int idx = tid + q * 256;
            int n4 = idx % (BN / 4), kr = idx / (BN / 4);
            r[q] = *(const float4*)(B + (size_t)(kc + kr) * BN + n4 * 4);
        }
    };
    auto writeA = [&](const float4* r) {
        #pragma unroll
        for (int q = 0; q < AREG; q++) {
            int idx = tid + q * 256;
            int m = idx >> 3, kq = idx & 7;
            As[kq * 4 + 0][m] = r[q].x;
            As[kq * 4 + 1][m] = r[q].y;
            As[kq * 4 + 2][m] = r[q].z;
            As[kq * 4 + 3][m] = r[q].w;
        }
    };
    auto writeB = [&](const float4* r) {
        #pragma unroll
        for (int q = 0; q < BREG; q++) {
            int idx = tid + q * 256;
            int n4 = idx % (BN / 4), kr = idx / (BN / 4);
            *(float4*)&Bs[kr][n4 * 4] = r[q];
        }
    };

    float acc[4][CPT];
    #pragma unroll
    for (int r = 0; r < 4; r++)
        #pragma unroll
        for (int c = 0; c < CPT; c++) acc[r][c] = 0.0f;

    // prologue: chunk 0 -> LDS; chunk 1 -> regs
    loadA(0, pa); loadB(0, pb);
    writeA(pa);   writeB(pb);
    if (NCH > 1) { loadA(1, pa); loadB(1, pb); }
    __syncthreads();

    for (int c = 0; c < NCH; c++) {
        #pragma unroll
        for (int kk = 0; kk < KC; kk++) {
            float4 a = *(const float4*)&As[kk][ty * 4];
            float av[4] = {a.x, a.y, a.z, a.w};
            float bv[CPT];
            float4 b0 = *(const float4*)&Bs[kk][tx * 4];
            bv[0] = b0.x; bv[1] = b0.y; bv[2] = b0.z; bv[3] = b0.w;
            if (BN == 128) {
                float4 b1 = *(const float4*)&Bs[kk][64 + tx * 4];
                bv[4] = b1.x; bv[5] = b1.y; bv[6] = b1.z; bv[7] = b1.w;
            }
            #pragma unroll
            for (int r = 0; r < 4; r++)
                #pragma unroll
                for (int cc = 0; cc < CPT; cc++)
                    acc[r][cc] += av[r] * bv[cc];
        }
        if (c + 1 < NCH) {
            __syncthreads();
            writeA(pa); writeB(pb);
            if (c + 2 < NCH) { loadA(c + 2, pa); loadB(c + 2, pb); }
            __syncthreads();
        }
    }

    // epilogue
    #pragma unroll
    for (int r = 0; r < 4; r++) {
        int row = row0 + ty * 4 + r;
        if (row >= M) continue;
        float4 o0;
        o0.x = acc[r][0]; o0.y = acc[r][1]; o0.z = acc[r][2]; o0.w = acc[r][3];
        if (BIAS) {
            o0.x += bias[tx * 4 + 0]; o0.y += bias[tx * 4 + 1];
            o0.z += bias[tx * 4 + 2]; o0.w += bias[tx * 4 + 3];
        }
        *(float4*)(C + (size_t)row * BN + tx * 4) = o0;
        if (BN == 128) {
            float4 o1;
            o1.x = acc[r][4]; o1.y = acc[r][5]; o1.z = acc[r][6]; o1.w = acc[r][7];
            if (BIAS) {
                o1.x += bias[64 + tx * 4 + 0]; o1.y += bias[64 + tx * 4 + 1];
                o1.z += bias[64 + tx * 4 + 2]; o1.w += bias[64 + tx * 4 + 3];
            }
            *(float4*)(C + (size_t)row * BN + 64 + tx * 4) = o1;
        }
    }
}

// ---------------------------------------------------------------------------
extern "C" void kernel_launch(void* const* d_in, const int* in_sizes, int n_in,
                              void* d_out, int out_size, void* d_ws, size_t ws_size,
                              hipStream_t stream) {
    const float* x       = (const float*)d_in[0];
    const float* W_in    = (const float*)d_in[1];
    const float* b_in    = (const float*)d_in[2];
    const float* W_self  = (const float*)d_in[3];
    const float* W_neigh = (const float*)d_in[4];
    const float* W_out   = (const float*)d_in[5];
    const float* b_out   = (const float*)d_in[6];
    const int*   eidx    = (const int*)d_in[7];

    const int N = 50000, E = 800000;
    const int* src = eidx;
    const int* dst = eidx + E;

    char* ws = (char*)d_ws;
    float* h   = (float*)(ws);                  // 25.6 MB
    float* hs  = (float*)(ws + 25600000);       // 25.6 MB
    float* agg = (float*)(ws + 51200000);       // 25.6 MB
    int* cnt     = (int*)(ws + 76800000);       // 200 KB
    int* row_ptr = (int*)(ws + 77000000);       // 200 KB
    int* cursor  = (int*)(ws + 77200016);       // 200 KB
    int* col     = (int*)(ws + 77400016);       // 3.2 MB

    hipMemsetAsync(cnt, 0, N * sizeof(int), stream);
    hist_kernel<<<(E + 255) / 256, 256, 0, stream>>>(src, cnt, E);
    scan_kernel<<<1, 1024, 0, stream>>>(cnt, row_ptr, cursor, N);
    scatter_kernel<<<(E + 255) / 256, 256, 0, stream>>>(src, dst, cursor, col, E);
    sortrows_kernel<<<(N + 3) / 4, 256, 0, stream>>>(row_ptr, col, N);

    // h = x @ W_in + b_in
    gemm_f32<128, false, true><<<(N + 63) / 64, 256, 0, stream>>>(
        x, W_in, nullptr, nullptr, b_in, h, N);

    for (int i = 0; i < 2; i++) {
        maxk_kernel<<<(N + 3) / 4, 256, 0, stream>>>(h, hs, N);
        aggregate_kernel<<<(N + 3) / 4, 256, 0, stream>>>(hs, row_ptr, col, agg, N);
        // h = hs @ W_self[i] + agg @ W_neigh[i]
        gemm_f32<128, true, false><<<(N + 63) / 64, 256, 0, stream>>>(
            hs, W_self + (size_t)i * KDIM * KDIM,
            agg, W_neigh + (size_t)i * KDIM * KDIM,
            nullptr, h, N);
    }

    // out = h @ W_out + b_out
    gemm_f32<64, false, true><<<(N + 63) / 64, 256, 0, stream>>>(
        h, W_out, nullptr, nullptr, b_out, (float*)d_out, N);
}

// Round 6
// 518.995 us; speedup vs baseline: 6.3891x; 6.3891x over previous
//
#include <hip/hip_runtime.h>

#define KDIM 128

// ---------------------------------------------------------------------------
// CSR build: histogram of src, exclusive scan, scatter (dst -> col), row sort
// ---------------------------------------------------------------------------
__global__ void hist_kernel(const int* __restrict__ src, int* __restrict__ cnt, int E) {
    int i = blockIdx.x * blockDim.x + threadIdx.x;
    if (i < E) atomicAdd(&cnt[src[i]], 1);
}

__global__ void scan_kernel(const int* __restrict__ cnt, int* __restrict__ row_ptr,
                            int* __restrict__ cursor, int N) {
    __shared__ int wsum[16];
    __shared__ int base_sh;
    const int tid = threadIdx.x;
    const int lane = tid & 63;
    const int w = tid >> 6;
    if (tid == 0) base_sh = 0;
    __syncthreads();
    for (int base = 0; base < N; base += 1024) {
        int i = base + tid;
        int v = (i < N) ? cnt[i] : 0;
        int x = v;
        #pragma unroll
        for (int off = 1; off < 64; off <<= 1) {
            int t = __shfl_up(x, off);
            if (lane >= off) x += t;
        }
        if (lane == 63) wsum[w] = x;
        __syncthreads();
        if (tid < 16) {
            int t = wsum[tid];
            #pragma unroll
            for (int off = 1; off < 16; off <<= 1) {
                int u = __shfl_up(t, off);
                if (tid >= off) t += u;
            }
            wsum[tid] = t;  // inclusive over waves
        }
        __syncthreads();
        int wexcl = (w == 0) ? 0 : wsum[w - 1];
        int excl = base_sh + wexcl + (x - v);
        if (i < N) { row_ptr[i] = excl; cursor[i] = excl; }
        int total = wsum[15];
        __syncthreads();
        if (tid == 0) base_sh += total;
        __syncthreads();
    }
    if (threadIdx.x == 0) row_ptr[N] = base_sh;
}

__global__ void scatter_kernel(const int* __restrict__ src, const int* __restrict__ dst,
                               int* cursor, int* __restrict__ col, int E) {
    int i = blockIdx.x * blockDim.x + threadIdx.x;
    if (i < E) {
        int p = atomicAdd(&cursor[src[i]], 1);
        col[p] = dst[i];
    }
}

// Sort each CSR row's col values ascending -> deterministic summation order.
__global__ void sortrows_kernel(const int* __restrict__ row_ptr, int* __restrict__ col, int M) {
    int wid = (blockIdx.x * blockDim.x + threadIdx.x) >> 6;
    int lane = threadIdx.x & 63;
    if (wid >= M) return;
    int s = row_ptr[wid], e = row_ptr[wid + 1], len = e - s;
    if (len <= 1) return;
    if (len <= 64) {
        int v = (lane < len) ? col[s + lane] : 0x7fffffff;
        #pragma unroll
        for (int k = 2; k <= 64; k <<= 1) {
            #pragma unroll
            for (int j = k >> 1; j > 0; j >>= 1) {
                int o = __shfl_xor(v, j);
                bool dir = ((lane & k) == 0);      // ascending block?
                bool smaller = ((lane & j) == 0);  // lower partner?
                int mn = min(v, o), mx = max(v, o);
                v = (dir == smaller) ? mn : mx;
            }
        }
        if (lane < len) col[s + lane] = v;
    } else if (lane == 0) {
        // rare fallback (deg > 64): insertion sort in global memory
        for (int a = s + 1; a < e; a++) {
            int key = col[a];
            int b = a - 1;
            while (b >= s && col[b] > key) { col[b + 1] = col[b]; b--; }
            col[b + 1] = key;
        }
    }
}

// ---------------------------------------------------------------------------
// MaxK: keep top-32 of 128 per row (jax.lax.top_k tie-break: lower index wins)
// One wave per row; ballot+popcount radix select (no cross-lane data moves).
// ---------------------------------------------------------------------------
__global__ void maxk_kernel(const float* __restrict__ h, float* __restrict__ hs, int M) {
    int wid = (blockIdx.x * blockDim.x + threadIdx.x) >> 6;
    int lane = threadIdx.x & 63;
    if (wid >= M) return;
    float2 v = ((const float2*)(h + (size_t)wid * KDIM))[lane];

    // orderable keys: larger float <-> larger uint
    unsigned int u0 = __float_as_uint(v.x);
    u0 = (u0 & 0x80000000u) ? ~u0 : (u0 | 0x80000000u);
    unsigned int u1 = __float_as_uint(v.y);
    u1 = (u1 & 0x80000000u) ? ~u1 : (u1 | 0x80000000u);

    // MSB radix select: find T = key of the 32nd largest element
    unsigned int prefix = 0;
    int remaining = 32;
    #pragma unroll
    for (int b = 31; b >= 0; --b) {
        unsigned int candHi = (prefix >> b) | 1u;  // high bits (31..b) of candidate
        unsigned long long m0 = __ballot((u0 >> b) == candHi);
        unsigned long long m1 = __ballot((u1 >> b) == candHi);
        int cnt = __popcll(m0) + __popcll(m1);
        if (cnt >= remaining) prefix |= (1u << b);
        else remaining -= cnt;
    }

    // keep all keys > T; among == T keep lowest element indices (idx = 2*lane+j)
    unsigned long long e0 = __ballot(u0 == prefix);
    unsigned long long e1 = __ballot(u1 == prefix);
    unsigned long long g0 = __ballot(u0 > prefix);
    unsigned long long g1 = __ballot(u1 > prefix);
    int quota = 32 - (__popcll(g0) + __popcll(g1));  // how many ==T to keep
    unsigned long long below = (1ULL << lane) - 1ULL;
    int rank0 = __popcll(e0 & below) + __popcll(e1 & below);
    int rank1 = rank0 + (int)((e0 >> lane) & 1ULL);
    bool k0 = (u0 > prefix) || (((e0 >> lane) & 1ULL) && rank0 < quota);
    bool k1 = (u1 > prefix) || (((e1 >> lane) & 1ULL) && rank1 < quota);

    float2 o;
    o.x = k0 ? v.x : 0.0f;
    o.y = k1 ? v.y : 0.0f;
    ((float2*)(hs + (size_t)wid * KDIM))[lane] = o;
}

// ---------------------------------------------------------------------------
// Aggregation: agg[s] = (sum over CSR row s of hs[col]) / (deg + 1e-6)
// One wave per node. 2 half-waves x 4-chain unroll = up to 8 independent
// 512B float4 row loads in flight per wave (latency hiding via MLP).
// Deterministic fixed combine order: chains 0..3, then half0 + half1.
// ---------------------------------------------------------------------------
__global__ __launch_bounds__(256)
void aggregate_kernel(const float* __restrict__ hs, const int* __restrict__ row_ptr,
                      const int* __restrict__ col, float* __restrict__ agg, int M) {
    const int lane = threadIdx.x & 63;
    const int wid = (blockIdx.x * blockDim.x + threadIdx.x) >> 6;
    if (wid >= M) return;
    const int half = lane >> 5;
    const int l32 = lane & 31;
    const int s = row_ptr[wid], e = row_ptr[wid + 1];
    const float4* __restrict__ hp = (const float4*)hs;  // row c -> hp[c*32 + l32]

    float4 a0 = make_float4(0.f, 0.f, 0.f, 0.f);
    float4 a1 = a0, a2 = a0, a3 = a0;

    int j = s + half;  // this half handles edges (j - s) even/odd per half
    for (; j + 6 < e; j += 8) {
        int c0 = col[j];
        int c1 = col[j + 2];
        int c2 = col[j + 4];
        int c3 = col[j + 6];
        float4 v0 = hp[(size_t)c0 * 32 + l32];
        float4 v1 = hp[(size_t)c1 * 32 + l32];
        float4 v2 = hp[(size_t)c2 * 32 + l32];
        float4 v3 = hp[(size_t)c3 * 32 + l32];
        a0.x += v0.x; a0.y += v0.y; a0.z += v0.z; a0.w += v0.w;
        a1.x += v1.x; a1.y += v1.y; a1.z += v1.z; a1.w += v1.w;
        a2.x += v2.x; a2.y += v2.y; a2.z += v2.z; a2.w += v2.w;
        a3.x += v3.x; a3.y += v3.y; a3.z += v3.z; a3.w += v3.w;
    }
    for (; j < e; j += 2) {  // tail for this half (deterministic: into a0)
        int c = col[j];
        float4 v = hp[(size_t)c * 32 + l32];
        a0.x += v.x; a0.y += v.y; a0.z += v.z; a0.w += v.w;
    }

    // combine chains in fixed order: ((a0 + a1) + a2) + a3
    float4 t;
    t.x = ((a0.x + a1.x) + a2.x) + a3.x;
    t.y = ((a0.y + a1.y) + a2.y) + a3.y;
    t.z = ((a0.z + a1.z) + a2.z) + a3.z;
    t.w = ((a0.w + a1.w) + a2.w) + a3.w;

    // cross-half combine: lane<32 gets half0 + half1 (fixed order)
    float4 u;
    u.x = __shfl_xor(t.x, 32);
    u.y = __shfl_xor(t.y, 32);
    u.z = __shfl_xor(t.z, 32);
    u.w = __shfl_xor(t.w, 32);

    if (half == 0) {
        float inv = 1.0f / ((float)(e - s) + 1e-6f);
        float4 o;
        o.x = (t.x + u.x) * inv;
        o.y = (t.y + u.y) * inv;
        o.z = (t.z + u.z) * inv;
        o.w = (t.w + u.w) * inv;
        ((float4*)(agg + (size_t)wid * KDIM))[l32] = o;
    }
}

// ---------------------------------------------------------------------------
// f32 GEMM: C[M,BN] = A1[M,128] @ B1[128,BN] (+ A2 @ B2) (+ bias)
// BM=64 (grid 782 -> ~3 blocks/CU), 256 threads, acc 4x(BN/16).
// Register prefetch of chunk c+1 while computing chunk c — all staging code
// INLINE with compile-time-constant array indices only (no lambdas / no
// array-pointer args: R5 showed those land the arrays in scratch -> 3.3 GB
// of spill traffic).
// ---------------------------------------------------------------------------
template <int BN, bool DUAL, bool BIAS>
__global__ __launch_bounds__(256)
void gemm_f32(const float* __restrict__ A1, const float* __restrict__ B1,
              const float* __restrict__ A2, const float* __restrict__ B2,
              const float* __restrict__ bias, float* __restrict__ C, int M) {
    constexpr int BM = 64;
    constexpr int KC = 32;
    constexpr int BMP = BM + 4;
    constexpr int BNP = BN + 4;
    constexpr int NK = KDIM / KC;          // 4 chunks per source
    constexpr int NCH = (DUAL ? 2 : 1) * NK;
    constexpr int CPT = BN / 16;           // cols per thread: 8 or 4
    constexpr int AREG = (BM * KC / 4) / 256;   // 2
    constexpr int BREG = (KC * BN / 4) / 256;   // 4 (BN=128) or 2 (BN=64)

    __shared__ float As[KC][BMP];   // transposed: As[k][m]
    __shared__ float Bs[KC][BNP];

    const int tid = threadIdx.x;
    const int tx = tid & 15;
    const int ty = tid >> 4;
    const int row0 = blockIdx.x * BM;

    // staging indices (constant per thread)
    const int am = tid >> 3;          // A: row within tile, 8 float4 per row
    const int akq = tid & 7;          // A: float4 index along K
    const int bn4 = tid % (BN / 4);   // B: float4 col
    const int bkr = tid / (BN / 4);   // B: k row
    const int bkstep = 1024 / BN;     // k rows advanced per 256-thread pass

    float4 pa[AREG], pb[BREG];

    // ---- load chunk 0 into regs (inline) ----
    {
        const float* A = A1; const float* B = B1; const int kc = 0;
        #pragma unroll
        for (int q = 0; q < AREG; q++) {
            int row = row0 + am + q * 32;
            pa[q] = (row < M) ? *(const float4*)(A + (size_t)row * KDIM + kc + akq * 4)
                              : make_float4(0.f, 0.f, 0.f, 0.f);
        }
        #pragma unroll
        for (int q = 0; q < BREG; q++)
            pb[q] = *(const float4*)(B + (size_t)(kc + bkr + q * bkstep) * BN + bn4 * 4);
    }

    float acc[4][CPT];
    #pragma unroll
    for (int r = 0; r < 4; r++)
        #pragma unroll
        for (int c = 0; c < CPT; c++) acc[r][c] = 0.0f;

    for (int c = 0; c < NCH; c++) {
        // ---- regs (chunk c) -> LDS ----
        #pragma unroll
        for (int q = 0; q < AREG; q++) {
            As[akq * 4 + 0][am + q * 32] = pa[q].x;
            As[akq * 4 + 1][am + q * 32] = pa[q].y;
            As[akq * 4 + 2][am + q * 32] = pa[q].z;
            As[akq * 4 + 3][am + q * 32] = pa[q].w;
        }
        #pragma unroll
        for (int q = 0; q < BREG; q++)
            *(float4*)&Bs[bkr + q * bkstep][bn4 * 4] = pb[q];
        __syncthreads();

        // ---- prefetch chunk c+1 into regs (overlaps with compute below) ----
        if (c + 1 < NCH) {
            const float* A = (DUAL && (c + 1) >= NK) ? A2 : A1;
            const float* B = (DUAL && (c + 1) >= NK) ? B2 : B1;
            const int kc = ((c + 1) & (NK - 1)) * KC;
            #pragma unroll
            for (int q = 0; q < AREG; q++) {
                int row = row0 + am + q * 32;
                pa[q] = (row < M) ? *(const float4*)(A + (size_t)row * KDIM + kc + akq * 4)
                                  : make_float4(0.f, 0.f, 0.f, 0.f);
            }
            #pragma unroll
            for (int q = 0; q < BREG; q++)
                pb[q] = *(const float4*)(B + (size_t)(kc + bkr + q * bkstep) * BN + bn4 * 4);
        }

        // ---- compute chunk c from LDS ----
        #pragma unroll
        for (int kk = 0; kk < KC; kk++) {
            float4 a = *(const float4*)&As[kk][ty * 4];
            float av[4] = {a.x, a.y, a.z, a.w};
            float bv[CPT];
            float4 b0 = *(const float4*)&Bs[kk][tx * 4];
            bv[0] = b0.x; bv[1] = b0.y; bv[2] = b0.z; bv[3] = b0.w;
            if (BN == 128) {
                float4 b1 = *(const float4*)&Bs[kk][64 + tx * 4];
                bv[4] = b1.x; bv[5] = b1.y; bv[6] = b1.z; bv[7] = b1.w;
            }
            #pragma unroll
            for (int r = 0; r < 4; r++)
                #pragma unroll
                for (int cc = 0; cc < CPT; cc++)
                    acc[r][cc] += av[r] * bv[cc];
        }
        __syncthreads();
    }

    // ---- epilogue ----
    #pragma unroll
    for (int r = 0; r < 4; r++) {
        int row = row0 + ty * 4 + r;
        if (row >= M) continue;
        float4 o0;
        o0.x = acc[r][0]; o0.y = acc[r][1]; o0.z = acc[r][2]; o0.w = acc[r][3];
        if (BIAS) {
            o0.x += bias[tx * 4 + 0]; o0.y += bias[tx * 4 + 1];
            o0.z += bias[tx * 4 + 2]; o0.w += bias[tx * 4 + 3];
        }
        *(float4*)(C + (size_t)row * BN + tx * 4) = o0;
        if (BN == 128) {
            float4 o1;
            o1.x = acc[r][4]; o1.y = acc[r][5]; o1.z = acc[r][6]; o1.w = acc[r][7];
            if (BIAS) {
                o1.x += bias[64 + tx * 4 + 0]; o1.y += bias[64 + tx * 4 + 1];
                o1.z += bias[64 + tx * 4 + 2]; o1.w += bias[64 + tx * 4 + 3];
            }
            *(float4*)(C + (size_t)row * BN + 64 + tx * 4) = o1;
        }
    }
}

// ---------------------------------------------------------------------------
extern "C" void kernel_launch(void* const* d_in, const int* in_sizes, int n_in,
                              void* d_out, int out_size, void* d_ws, size_t ws_size,
                              hipStream_t stream) {
    const float* x       = (const float*)d_in[0];
    const float* W_in    = (const float*)d_in[1];
    const float* b_in    = (const float*)d_in[2];
    const float* W_self  = (const float*)d_in[3];
    const float* W_neigh = (const float*)d_in[4];
    const float* W_out   = (const float*)d_in[5];
    const float* b_out   = (const float*)d_in[6];
    const int*   eidx    = (const int*)d_in[7];

    const int N = 50000, E = 800000;
    const int* src = eidx;
    const int* dst = eidx + E;

    char* ws = (char*)d_ws;
    float* h   = (float*)(ws);                  // 25.6 MB
    float* hs  = (float*)(ws + 25600000);       // 25.6 MB
    float* agg = (float*)(ws + 51200000);       // 25.6 MB
    int* cnt     = (int*)(ws + 76800000);       // 200 KB
    int* row_ptr = (int*)(ws + 77000000);       // 200 KB
    int* cursor  = (int*)(ws + 77200016);       // 200 KB
    int* col     = (int*)(ws + 77400016);       // 3.2 MB

    hipMemsetAsync(cnt, 0, N * sizeof(int), stream);
    hist_kernel<<<(E + 255) / 256, 256, 0, stream>>>(src, cnt, E);
    scan_kernel<<<1, 1024, 0, stream>>>(cnt, row_ptr, cursor, N);
    scatter_kernel<<<(E + 255) / 256, 256, 0, stream>>>(src, dst, cursor, col, E);
    sortrows_kernel<<<(N + 3) / 4, 256, 0, stream>>>(row_ptr, col, N);

    // h = x @ W_in + b_in
    gemm_f32<128, false, true><<<(N + 63) / 64, 256, 0, stream>>>(
        x, W_in, nullptr, nullptr, b_in, h, N);

    for (int i = 0; i < 2; i++) {
        maxk_kernel<<<(N + 3) / 4, 256, 0, stream>>>(h, hs, N);
        aggregate_kernel<<<(N + 3) / 4, 256, 0, stream>>>(hs, row_ptr, col, agg, N);
        // h = hs @ W_self[i] + agg @ W_neigh[i]
        gemm_f32<128, true, false><<<(N + 63) / 64, 256, 0, stream>>>(
            hs, W_self + (size_t)i * KDIM * KDIM,
            agg, W_neigh + (size_t)i * KDIM * KDIM,
            nullptr, h, N);
    }

    // out = h @ W_out + b_out
    gemm_f32<64, false, true><<<(N + 63) / 64, 256, 0, stream>>>(
        h, W_out, nullptr, nullptr, b_out, (float*)d_out, N);
}

// Round 7
// 431.556 us; speedup vs baseline: 7.6836x; 1.2026x over previous
//
#include <hip/hip_runtime.h>

#define KDIM 128

typedef _Float16 f16x8 __attribute__((ext_vector_type(8)));
typedef _Float16 f16x4 __attribute__((ext_vector_type(4)));
typedef float f32x16 __attribute__((ext_vector_type(16)));

// ---------------------------------------------------------------------------
// CSR build: histogram of src, exclusive scan, scatter (dst -> col), row sort
// ---------------------------------------------------------------------------
__global__ void hist_kernel(const int* __restrict__ src, int* __restrict__ cnt, int E) {
    int i = blockIdx.x * blockDim.x + threadIdx.x;
    if (i < E) atomicAdd(&cnt[src[i]], 1);
}

__global__ void scan_kernel(const int* __restrict__ cnt, int* __restrict__ row_ptr,
                            int* __restrict__ cursor, int N) {
    __shared__ int wsum[16];
    __shared__ int base_sh;
    const int tid = threadIdx.x;
    const int lane = tid & 63;
    const int w = tid >> 6;
    if (tid == 0) base_sh = 0;
    __syncthreads();
    for (int base = 0; base < N; base += 1024) {
        int i = base + tid;
        int v = (i < N) ? cnt[i] : 0;
        int x = v;
        #pragma unroll
        for (int off = 1; off < 64; off <<= 1) {
            int t = __shfl_up(x, off);
            if (lane >= off) x += t;
        }
        if (lane == 63) wsum[w] = x;
        __syncthreads();
        if (tid < 16) {
            int t = wsum[tid];
            #pragma unroll
            for (int off = 1; off < 16; off <<= 1) {
                int u = __shfl_up(t, off);
                if (tid >= off) t += u;
            }
            wsum[tid] = t;  // inclusive over waves
        }
        __syncthreads();
        int wexcl = (w == 0) ? 0 : wsum[w - 1];
        int excl = base_sh + wexcl + (x - v);
        if (i < N) { row_ptr[i] = excl; cursor[i] = excl; }
        int total = wsum[15];
        __syncthreads();
        if (tid == 0) base_sh += total;
        __syncthreads();
    }
    if (threadIdx.x == 0) row_ptr[N] = base_sh;
}

__global__ void scatter_kernel(const int* __restrict__ src, const int* __restrict__ dst,
                               int* cursor, int* __restrict__ col, int E) {
    int i = blockIdx.x * blockDim.x + threadIdx.x;
    if (i < E) {
        int p = atomicAdd(&cursor[src[i]], 1);
        col[p] = dst[i];
    }
}

// Sort each CSR row's col values ascending -> deterministic summation order.
__global__ void sortrows_kernel(const int* __restrict__ row_ptr, int* __restrict__ col, int M) {
    int wid = (blockIdx.x * blockDim.x + threadIdx.x) >> 6;
    int lane = threadIdx.x & 63;
    if (wid >= M) return;
    int s = row_ptr[wid], e = row_ptr[wid + 1], len = e - s;
    if (len <= 1) return;
    if (len <= 64) {
        int v = (lane < len) ? col[s + lane] : 0x7fffffff;
        #pragma unroll
        for (int k = 2; k <= 64; k <<= 1) {
            #pragma unroll
            for (int j = k >> 1; j > 0; j >>= 1) {
                int o = __shfl_xor(v, j);
                bool dir = ((lane & k) == 0);
                bool smaller = ((lane & j) == 0);
                int mn = min(v, o), mx = max(v, o);
                v = (dir == smaller) ? mn : mx;
            }
        }
        if (lane < len) col[s + lane] = v;
    } else if (lane == 0) {
        for (int a = s + 1; a < e; a++) {
            int key = col[a];
            int b = a - 1;
            while (b >= s && col[b] > key) { col[b + 1] = col[b]; b--; }
            col[b + 1] = key;
        }
    }
}

// ---------------------------------------------------------------------------
// MaxK: keep top-32 of 128 per row (jax.lax.top_k tie-break: lower index wins)
// ---------------------------------------------------------------------------
__global__ void maxk_kernel(const float* __restrict__ h, float* __restrict__ hs, int M) {
    int wid = (blockIdx.x * blockDim.x + threadIdx.x) >> 6;
    int lane = threadIdx.x & 63;
    if (wid >= M) return;
    float2 v = ((const float2*)(h + (size_t)wid * KDIM))[lane];

    unsigned int u0 = __float_as_uint(v.x);
    u0 = (u0 & 0x80000000u) ? ~u0 : (u0 | 0x80000000u);
    unsigned int u1 = __float_as_uint(v.y);
    u1 = (u1 & 0x80000000u) ? ~u1 : (u1 | 0x80000000u);

    unsigned int prefix = 0;
    int remaining = 32;
    #pragma unroll
    for (int b = 31; b >= 0; --b) {
        unsigned int candHi = (prefix >> b) | 1u;
        unsigned long long m0 = __ballot((u0 >> b) == candHi);
        unsigned long long m1 = __ballot((u1 >> b) == candHi);
        int cnt = __popcll(m0) + __popcll(m1);
        if (cnt >= remaining) prefix |= (1u << b);
        else remaining -= cnt;
    }

    unsigned long long e0 = __ballot(u0 == prefix);
    unsigned long long e1 = __ballot(u1 == prefix);
    unsigned long long g0 = __ballot(u0 > prefix);
    unsigned long long g1 = __ballot(u1 > prefix);
    int quota = 32 - (__popcll(g0) + __popcll(g1));
    unsigned long long below = (1ULL << lane) - 1ULL;
    int rank0 = __popcll(e0 & below) + __popcll(e1 & below);
    int rank1 = rank0 + (int)((e0 >> lane) & 1ULL);
    bool k0 = (u0 > prefix) || (((e0 >> lane) & 1ULL) && rank0 < quota);
    bool k1 = (u1 > prefix) || (((e1 >> lane) & 1ULL) && rank1 < quota);

    float2 o;
    o.x = k0 ? v.x : 0.0f;
    o.y = k1 ? v.y : 0.0f;
    ((float2*)(hs + (size_t)wid * KDIM))[lane] = o;
}

// ---------------------------------------------------------------------------
// Aggregation: agg[s] = (sum over CSR row s of hs[col]) / (deg + 1e-6)
// ---------------------------------------------------------------------------
__global__ __launch_bounds__(256)
void aggregate_kernel(const float* __restrict__ hs, const int* __restrict__ row_ptr,
                      const int* __restrict__ col, float* __restrict__ agg, int M) {
    const int lane = threadIdx.x & 63;
    const int wid = (blockIdx.x * blockDim.x + threadIdx.x) >> 6;
    if (wid >= M) return;
    const int half = lane >> 5;
    const int l32 = lane & 31;
    const int s = row_ptr[wid], e = row_ptr[wid + 1];
    const float4* __restrict__ hp = (const float4*)hs;

    float4 a0 = make_float4(0.f, 0.f, 0.f, 0.f);
    float4 a1 = a0, a2 = a0, a3 = a0;

    int j = s + half;
    for (; j + 6 < e; j += 8) {
        int c0 = col[j];
        int c1 = col[j + 2];
        int c2 = col[j + 4];
        int c3 = col[j + 6];
        float4 v0 = hp[(size_t)c0 * 32 + l32];
        float4 v1 = hp[(size_t)c1 * 32 + l32];
        float4 v2 = hp[(size_t)c2 * 32 + l32];
        float4 v3 = hp[(size_t)c3 * 32 + l32];
        a0.x += v0.x; a0.y += v0.y; a0.z += v0.z; a0.w += v0.w;
        a1.x += v1.x; a1.y += v1.y; a1.z += v1.z; a1.w += v1.w;
        a2.x += v2.x; a2.y += v2.y; a2.z += v2.z; a2.w += v2.w;
        a3.x += v3.x; a3.y += v3.y; a3.z += v3.z; a3.w += v3.w;
    }
    for (; j < e; j += 2) {
        int c = col[j];
        float4 v = hp[(size_t)c * 32 + l32];
        a0.x += v.x; a0.y += v.y; a0.z += v.z; a0.w += v.w;
    }

    float4 t;
    t.x = ((a0.x + a1.x) + a2.x) + a3.x;
    t.y = ((a0.y + a1.y) + a2.y) + a3.y;
    t.z = ((a0.z + a1.z) + a2.z) + a3.z;
    t.w = ((a0.w + a1.w) + a2.w) + a3.w;

    float4 u;
    u.x = __shfl_xor(t.x, 32);
    u.y = __shfl_xor(t.y, 32);
    u.z = __shfl_xor(t.z, 32);
    u.w = __shfl_xor(t.w, 32);

    if (half == 0) {
        float inv = 1.0f / ((float)(e - s) + 1e-6f);
        float4 o;
        o.x = (t.x + u.x) * inv;
        o.y = (t.y + u.y) * inv;
        o.z = (t.z + u.z) * inv;
        o.w = (t.w + u.w) * inv;
        ((float4*)(agg + (size_t)wid * KDIM))[l32] = o;
    }
}

// ---------------------------------------------------------------------------
// Weight prep: transpose to [n][k] and split f32 -> fp16 (hi, lo).
// wb slots of 16384 fp16: 0/1 WinT h/l; 2+2i/3+2i WsT[i]; 6+2i/7+2i WnT[i];
// 10/11 WoutT (64x128, 8192 used).
// ---------------------------------------------------------------------------
__global__ void conv_wt_kernel(const float* __restrict__ W_in,
                               const float* __restrict__ W_self,
                               const float* __restrict__ W_neigh,
                               const float* __restrict__ W_out,
                               _Float16* __restrict__ wb) {
    int t = blockIdx.x * blockDim.x + threadIdx.x;
    if (t < 81920) {
        int m = t >> 14;            // 0..4
        int e = t & 16383;
        int n = e >> 7, k = e & 127;
        const float* S = (m == 0) ? W_in
                       : (m <= 2) ? (W_self + (size_t)(m - 1) * 16384)
                                  : (W_neigh + (size_t)(m - 3) * 16384);
        float v = S[k * 128 + n];
        _Float16 hi = (_Float16)v;
        _Float16 lo = (_Float16)(v - (float)hi);
        int pair = m * 2;
        wb[(size_t)pair * 16384 + n * 128 + k] = hi;
        wb[(size_t)(pair + 1) * 16384 + n * 128 + k] = lo;
    } else if (t < 90112) {
        int e = t - 81920;          // [0, 8192)
        int n = e >> 7, k = e & 127;
        float v = W_out[k * 64 + n];
        _Float16 hi = (_Float16)v;
        _Float16 lo = (_Float16)(v - (float)hi);
        wb[(size_t)10 * 16384 + e] = hi;
        wb[(size_t)11 * 16384 + e] = lo;
    }
}

// ---------------------------------------------------------------------------
// Split-fp16 MFMA GEMM: C[M,BN] = A1 @ B1 (+ A2 @ B2) (+ bias), K=128, f32 I/O.
// Each f32 operand is split a = hi + lo (fp16); a@b = hi@hi + hi@lo + lo@hi
// (lo@lo term ~2^-22 rel, dropped) -> ~f32-grade accuracy at MFMA rate.
// Block: 64 rows x BN cols, 4 waves, mfma_f32_32x32x16_f16.
// A staged once in LDS (full K, hi/lo, XOR-swizzled vs the 256B-row 32-way
// bank conflict); single barrier; B read from L1-resident pre-transposed
// global ([n][k] fp16).
// Frag maps: A row=lane&31, k=(lane>>5)*8+j; B col=lane&31, same k;
// C/D col=lane&31, row=(reg&3)+8*(reg>>2)+4*(lane>>5)  [m74/m101].
// ---------------------------------------------------------------------------
template <int BN, bool DUAL, bool BIAS>
__global__ __launch_bounds__(256)
void gemm_mfma(const float* __restrict__ A1, const float* __restrict__ A2,
               const _Float16* __restrict__ B1h, const _Float16* __restrict__ B1l,
               const _Float16* __restrict__ B2h, const _Float16* __restrict__ B2l,
               const float* __restrict__ bias, float* __restrict__ C, int M) {
    constexpr int NSRC = DUAL ? 2 : 1;
    constexpr int NT = BN / 32;      // n-tiles in block: 4 or 2
    constexpr int TPW = NT / 2;      // m-tiles per wave: 2 (BN=128) or 1 (BN=64)

    __shared__ __align__(16) char Alds[NSRC * 2 * 64 * 256];  // [src][h/l][row][256B]

    const int tid = threadIdx.x;
    const int w = tid >> 6;
    const int lane = tid & 63;
    const int l31 = lane & 31;
    const int kslot = lane >> 5;
    const int row0 = blockIdx.x * 64;

    // ---- stage A: f32 -> (hi,lo) fp16 into swizzled LDS ----
    for (int s = 0; s < NSRC; s++) {
        const float* A = s ? A2 : A1;
        #pragma unroll
        for (int p = 0; p < 8; p++) {
            int idx = tid + p * 256;
            int row = idx >> 5, k4 = idx & 31;
            float4 v = make_float4(0.f, 0.f, 0.f, 0.f);
            if (row0 + row < M) v = *(const float4*)(A + (size_t)(row0 + row) * KDIM + k4 * 4);
            _Float16 h0 = (_Float16)v.x, h1 = (_Float16)v.y,
                     h2 = (_Float16)v.z, h3 = (_Float16)v.w;
            f16x4 hv = {h0, h1, h2, h3};
            f16x4 lv = {(_Float16)(v.x - (float)h0), (_Float16)(v.y - (float)h1),
                        (_Float16)(v.z - (float)h2), (_Float16)(v.w - (float)h3)};
            int boff = (k4 * 8) ^ ((row & 7) << 4);
            *(f16x4*)(Alds + (s * 2 + 0) * 16384 + row * 256 + boff) = hv;
            *(f16x4*)(Alds + (s * 2 + 1) * 16384 + row * 256 + boff) = lv;
        }
    }
    __syncthreads();

    const int n0 = (BN == 128) ? w * 32 : (w & 1) * 32;
    const int mt0 = (BN == 128) ? 0 : (w >> 1);

    f32x16 acc[TPW];
    #pragma unroll
    for (int t = 0; t < TPW; t++)
        #pragma unroll
        for (int e = 0; e < 16; e++) acc[t][e] = 0.0f;

    for (int s = 0; s < NSRC; s++) {
        const _Float16* Bh = s ? B2h : B1h;
        const _Float16* Bl = s ? B2l : B1l;
        const _Float16* bph = Bh + (size_t)(n0 + l31) * 128 + kslot * 8;
        const _Float16* bpl = Bl + (size_t)(n0 + l31) * 128 + kslot * 8;
        const char* abase = Alds + (size_t)(s * 2) * 16384;
        #pragma unroll
        for (int kb = 0; kb < 8; kb++) {
            f16x8 bh = *(const f16x8*)(bph + kb * 16);
            f16x8 bl = *(const f16x8*)(bpl + kb * 16);
            #pragma unroll
            for (int t = 0; t < TPW; t++) {
                int row = (mt0 + t) * 32 + l31;
                int boff = ((kb * 2 + kslot) * 16) ^ ((row & 7) << 4);
                const char* rp = abase + row * 256 + boff;
                f16x8 ah = *(const f16x8*)(rp);
                f16x8 al = *(const f16x8*)(rp + 16384);
                acc[t] = __builtin_amdgcn_mfma_f32_32x32x16_f16(al, bh, acc[t], 0, 0, 0);
                acc[t] = __builtin_amdgcn_mfma_f32_32x32x16_f16(ah, bl, acc[t], 0, 0, 0);
                acc[t] = __builtin_amdgcn_mfma_f32_32x32x16_f16(ah, bh, acc[t], 0, 0, 0);
            }
        }
    }

    float bv = 0.0f;
    if (BIAS) bv = bias[n0 + l31];
    #pragma unroll
    for (int t = 0; t < TPW; t++) {
        #pragma unroll
        for (int r = 0; r < 16; r++) {
            int row = row0 + (mt0 + t) * 32 + (r & 3) + 8 * (r >> 2) + 4 * kslot;
            if (row < M) C[(size_t)row * BN + n0 + l31] = acc[t][r] + bv;
        }
    }
}

// ---------------------------------------------------------------------------
extern "C" void kernel_launch(void* const* d_in, const int* in_sizes, int n_in,
                              void* d_out, int out_size, void* d_ws, size_t ws_size,
                              hipStream_t stream) {
    const float* x       = (const float*)d_in[0];
    const float* W_in    = (const float*)d_in[1];
    const float* b_in    = (const float*)d_in[2];
    const float* W_self  = (const float*)d_in[3];
    const float* W_neigh = (const float*)d_in[4];
    const float* W_out   = (const float*)d_in[5];
    const float* b_out   = (const float*)d_in[6];
    const int*   eidx    = (const int*)d_in[7];

    const int N = 50000, E = 800000;
    const int* src = eidx;
    const int* dst = eidx + E;

    char* ws = (char*)d_ws;
    float* h   = (float*)(ws);                  // 25.6 MB
    float* hs  = (float*)(ws + 25600000);       // 25.6 MB
    float* agg = (float*)(ws + 51200000);       // 25.6 MB
    int* cnt     = (int*)(ws + 76800000);       // 200 KB
    int* row_ptr = (int*)(ws + 77000000);       // 200 KB
    int* cursor  = (int*)(ws + 77200016);       // 200 KB
    int* col     = (int*)(ws + 77400016);       // 3.2 MB
    _Float16* wb = (_Float16*)(ws + 80600016);  // 384 KB weight slots

    const _Float16* WinT_h  = wb + (size_t)0 * 16384;
    const _Float16* WinT_l  = wb + (size_t)1 * 16384;
    const _Float16* WoutT_h = wb + (size_t)10 * 16384;
    const _Float16* WoutT_l = wb + (size_t)11 * 16384;

    hipMemsetAsync(cnt, 0, N * sizeof(int), stream);
    hist_kernel<<<(E + 255) / 256, 256, 0, stream>>>(src, cnt, E);
    scan_kernel<<<1, 1024, 0, stream>>>(cnt, row_ptr, cursor, N);
    scatter_kernel<<<(E + 255) / 256, 256, 0, stream>>>(src, dst, cursor, col, E);
    sortrows_kernel<<<(N + 3) / 4, 256, 0, stream>>>(row_ptr, col, N);
    conv_wt_kernel<<<(90112 + 255) / 256, 256, 0, stream>>>(W_in, W_self, W_neigh, W_out, wb);

    const int G = (N + 63) / 64;  // 782

    // h = x @ W_in + b_in
    gemm_mfma<128, false, true><<<G, 256, 0, stream>>>(
        x, nullptr, WinT_h, WinT_l, nullptr, nullptr, b_in, h, N);

    for (int i = 0; i < 2; i++) {
        maxk_kernel<<<(N + 3) / 4, 256, 0, stream>>>(h, hs, N);
        aggregate_kernel<<<(N + 3) / 4, 256, 0, stream>>>(hs, row_ptr, col, agg, N);
        const _Float16* WsT_h = wb + (size_t)(2 + 2 * i) * 16384;
        const _Float16* WsT_l = wb + (size_t)(3 + 2 * i) * 16384;
        const _Float16* WnT_h = wb + (size_t)(6 + 2 * i) * 16384;
        const _Float16* WnT_l = wb + (size_t)(7 + 2 * i) * 16384;
        // h = hs @ W_self[i] + agg @ W_neigh[i]
        gemm_mfma<128, true, false><<<G, 256, 0, stream>>>(
            hs, agg, WsT_h, WsT_l, WnT_h, WnT_l, nullptr, h, N);
    }

    // out = h @ W_out + b_out
    gemm_mfma<64, false, true><<<G, 256, 0, stream>>>(
        h, nullptr, WoutT_h, WoutT_l, nullptr, nullptr, b_out, (float*)d_out, N);
}

// Round 8
// 375.870 us; speedup vs baseline: 8.8219x; 1.1482x over previous
//
#include <hip/hip_runtime.h>

#define KDIM 128

typedef _Float16 f16x8 __attribute__((ext_vector_type(8)));
typedef _Float16 f16x4 __attribute__((ext_vector_type(4)));
typedef float f32x16 __attribute__((ext_vector_type(16)));

// ---------------------------------------------------------------------------
// CSR build. hist/scatter are XCD-chunked: block = (chunk<<3)|r, node-range r
// on (round-robin-dispatched) XCD r -> cnt/cursor atomics and col writes stay
// XCD-L2-local (fixes 52MB of cross-XCD line ping-pong writebacks, R7).
// ---------------------------------------------------------------------------
#define NRANGE 6250   // 50000 / 8
#define ECHUNK 3200   // edges per chunk; chunks = ceil(E/3200) = 250

__global__ void hist_kernel(const int* __restrict__ src, int* __restrict__ cnt, int E) {
    const int r = blockIdx.x & 7;
    const int chunk = blockIdx.x >> 3;
    const int lo = r * NRANGE, hi = lo + NRANGE;
    const int base = chunk * ECHUNK;
    const int end = min(base + ECHUNK, E);
    for (int i = base + threadIdx.x; i < end; i += 256) {
        int s = src[i];
        if (s >= lo && s < hi) atomicAdd(&cnt[s], 1);
    }
}

__global__ void scatter_kernel(const int* __restrict__ src, const int* __restrict__ dst,
                               int* cursor, int* __restrict__ col, int E) {
    const int r = blockIdx.x & 7;
    const int chunk = blockIdx.x >> 3;
    const int lo = r * NRANGE, hi = lo + NRANGE;
    const int base = chunk * ECHUNK;
    const int end = min(base + ECHUNK, E);
    for (int i = base + threadIdx.x; i < end; i += 256) {
        int s = src[i];
        if (s >= lo && s < hi) {
            int p = atomicAdd(&cursor[s], 1);
            col[p] = dst[i];
        }
    }
}

// Hierarchical exclusive scan of cnt[0..N) -> row_ptr, cursor (3 kernels).
__global__ void scan1_kernel(const int* __restrict__ cnt, int* __restrict__ row_ptr,
                             int* __restrict__ bsum, int N) {
    __shared__ int ws[4];
    const int t = threadIdx.x;
    const int lane = t & 63, w = t >> 6;
    const int i = blockIdx.x * 256 + t;
    int v = (i < N) ? cnt[i] : 0;
    int x = v;
    #pragma unroll
    for (int off = 1; off < 64; off <<= 1) {
        int u = __shfl_up(x, off);
        if (lane >= off) x += u;
    }
    if (lane == 63) ws[w] = x;
    __syncthreads();
    int wexcl = 0;
    #pragma unroll
    for (int k = 0; k < 4; k++) wexcl += (k < w) ? ws[k] : 0;
    if (i < N) row_ptr[i] = wexcl + x - v;      // block-local exclusive
    if (t == 255) bsum[blockIdx.x] = wexcl + x; // block total
}

__global__ void scan2_kernel(int* __restrict__ bsum, int NB) {
    __shared__ int ws[4];
    const int t = threadIdx.x;
    const int lane = t & 63, w = t >> 6;
    int v = (t < NB) ? bsum[t] : 0;
    int x = v;
    #pragma unroll
    for (int off = 1; off < 64; off <<= 1) {
        int u = __shfl_up(x, off);
        if (lane >= off) x += u;
    }
    if (lane == 63) ws[w] = x;
    __syncthreads();
    int wexcl = 0;
    #pragma unroll
    for (int k = 0; k < 4; k++) wexcl += (k < w) ? ws[k] : 0;
    if (t < NB) bsum[t] = wexcl + x - v;        // exclusive block offsets
}

__global__ void scan3_kernel(const int* __restrict__ bsum, int* __restrict__ row_ptr,
                             int* __restrict__ cursor, int N, int E) {
    const int i = blockIdx.x * 256 + threadIdx.x;
    if (i < N) {
        int v = row_ptr[i] + bsum[blockIdx.x];
        row_ptr[i] = v;
        cursor[i] = v;
    }
    if (i == 0) row_ptr[N] = E;
}

// Sort each CSR row's col values ascending -> deterministic summation order.
__global__ void sortrows_kernel(const int* __restrict__ row_ptr, int* __restrict__ col, int M) {
    int wid = (blockIdx.x * blockDim.x + threadIdx.x) >> 6;
    int lane = threadIdx.x & 63;
    if (wid >= M) return;
    int s = row_ptr[wid], e = row_ptr[wid + 1], len = e - s;
    if (len <= 1) return;
    if (len <= 64) {
        int v = (lane < len) ? col[s + lane] : 0x7fffffff;
        #pragma unroll
        for (int k = 2; k <= 64; k <<= 1) {
            #pragma unroll
            for (int j = k >> 1; j > 0; j >>= 1) {
                int o = __shfl_xor(v, j);
                bool dir = ((lane & k) == 0);
                bool smaller = ((lane & j) == 0);
                int mn = min(v, o), mx = max(v, o);
                v = (dir == smaller) ? mn : mx;
            }
        }
        if (lane < len) col[s + lane] = v;
    } else if (lane == 0) {
        for (int a = s + 1; a < e; a++) {
            int key = col[a];
            int b = a - 1;
            while (b >= s && col[b] > key) { col[b + 1] = col[b]; b--; }
            col[b + 1] = key;
        }
    }
}

// ---------------------------------------------------------------------------
// MaxK: keep top-32 of 128 per row (jax.lax.top_k tie-break: lower index wins)
// ---------------------------------------------------------------------------
__global__ void maxk_kernel(const float* __restrict__ h, float* __restrict__ hs, int M) {
    int wid = (blockIdx.x * blockDim.x + threadIdx.x) >> 6;
    int lane = threadIdx.x & 63;
    if (wid >= M) return;
    float2 v = ((const float2*)(h + (size_t)wid * KDIM))[lane];

    unsigned int u0 = __float_as_uint(v.x);
    u0 = (u0 & 0x80000000u) ? ~u0 : (u0 | 0x80000000u);
    unsigned int u1 = __float_as_uint(v.y);
    u1 = (u1 & 0x80000000u) ? ~u1 : (u1 | 0x80000000u);

    unsigned int prefix = 0;
    int remaining = 32;
    #pragma unroll
    for (int b = 31; b >= 0; --b) {
        unsigned int candHi = (prefix >> b) | 1u;
        unsigned long long m0 = __ballot((u0 >> b) == candHi);
        unsigned long long m1 = __ballot((u1 >> b) == candHi);
        int cnt = __popcll(m0) + __popcll(m1);
        if (cnt >= remaining) prefix |= (1u << b);
        else remaining -= cnt;
    }

    unsigned long long e0 = __ballot(u0 == prefix);
    unsigned long long e1 = __ballot(u1 == prefix);
    unsigned long long g0 = __ballot(u0 > prefix);
    unsigned long long g1 = __ballot(u1 > prefix);
    int quota = 32 - (__popcll(g0) + __popcll(g1));
    unsigned long long below = (1ULL << lane) - 1ULL;
    int rank0 = __popcll(e0 & below) + __popcll(e1 & below);
    int rank1 = rank0 + (int)((e0 >> lane) & 1ULL);
    bool k0 = (u0 > prefix) || (((e0 >> lane) & 1ULL) && rank0 < quota);
    bool k1 = (u1 > prefix) || (((e1 >> lane) & 1ULL) && rank1 < quota);

    float2 o;
    o.x = k0 ? v.x : 0.0f;
    o.y = k1 ? v.y : 0.0f;
    ((float2*)(hs + (size_t)wid * KDIM))[lane] = o;
}

// ---------------------------------------------------------------------------
// Aggregation: agg[s] = (sum over CSR row s of hs[col]) / (deg + 1e-6)
// ---------------------------------------------------------------------------
__global__ __launch_bounds__(256)
void aggregate_kernel(const float* __restrict__ hs, const int* __restrict__ row_ptr,
                      const int* __restrict__ col, float* __restrict__ agg, int M) {
    const int lane = threadIdx.x & 63;
    const int wid = (blockIdx.x * blockDim.x + threadIdx.x) >> 6;
    if (wid >= M) return;
    const int half = lane >> 5;
    const int l32 = lane & 31;
    const int s = row_ptr[wid], e = row_ptr[wid + 1];
    const float4* __restrict__ hp = (const float4*)hs;

    float4 a0 = make_float4(0.f, 0.f, 0.f, 0.f);
    float4 a1 = a0, a2 = a0, a3 = a0;

    int j = s + half;
    for (; j + 6 < e; j += 8) {
        int c0 = col[j];
        int c1 = col[j + 2];
        int c2 = col[j + 4];
        int c3 = col[j + 6];
        float4 v0 = hp[(size_t)c0 * 32 + l32];
        float4 v1 = hp[(size_t)c1 * 32 + l32];
        float4 v2 = hp[(size_t)c2 * 32 + l32];
        float4 v3 = hp[(size_t)c3 * 32 + l32];
        a0.x += v0.x; a0.y += v0.y; a0.z += v0.z; a0.w += v0.w;
        a1.x += v1.x; a1.y += v1.y; a1.z += v1.z; a1.w += v1.w;
        a2.x += v2.x; a2.y += v2.y; a2.z += v2.z; a2.w += v2.w;
        a3.x += v3.x; a3.y += v3.y; a3.z += v3.z; a3.w += v3.w;
    }
    for (; j < e; j += 2) {
        int c = col[j];
        float4 v = hp[(size_t)c * 32 + l32];
        a0.x += v.x; a0.y += v.y; a0.z += v.z; a0.w += v.w;
    }

    float4 t;
    t.x = ((a0.x + a1.x) + a2.x) + a3.x;
    t.y = ((a0.y + a1.y) + a2.y) + a3.y;
    t.z = ((a0.z + a1.z) + a2.z) + a3.z;
    t.w = ((a0.w + a1.w) + a2.w) + a3.w;

    float4 u;
    u.x = __shfl_xor(t.x, 32);
    u.y = __shfl_xor(t.y, 32);
    u.z = __shfl_xor(t.z, 32);
    u.w = __shfl_xor(t.w, 32);

    if (half == 0) {
        float inv = 1.0f / ((float)(e - s) + 1e-6f);
        float4 o;
        o.x = (t.x + u.x) * inv;
        o.y = (t.y + u.y) * inv;
        o.z = (t.z + u.z) * inv;
        o.w = (t.w + u.w) * inv;
        ((float4*)(agg + (size_t)wid * KDIM))[l32] = o;
    }
}

// ---------------------------------------------------------------------------
// Weight prep: transpose to [n][k] and split f32 -> fp16 (hi, lo).
// ---------------------------------------------------------------------------
__global__ void conv_wt_kernel(const float* __restrict__ W_in,
                               const float* __restrict__ W_self,
                               const float* __restrict__ W_neigh,
                               const float* __restrict__ W_out,
                               _Float16* __restrict__ wb) {
    int t = blockIdx.x * blockDim.x + threadIdx.x;
    if (t < 81920) {
        int m = t >> 14;            // 0..4
        int e = t & 16383;
        int n = e >> 7, k = e & 127;
        const float* S = (m == 0) ? W_in
                       : (m <= 2) ? (W_self + (size_t)(m - 1) * 16384)
                                  : (W_neigh + (size_t)(m - 3) * 16384);
        float v = S[k * 128 + n];
        _Float16 hi = (_Float16)v;
        _Float16 lo = (_Float16)(v - (float)hi);
        int pair = m * 2;
        wb[(size_t)pair * 16384 + n * 128 + k] = hi;
        wb[(size_t)(pair + 1) * 16384 + n * 128 + k] = lo;
    } else if (t < 90112) {
        int e = t - 81920;          // [0, 8192)
        int n = e >> 7, k = e & 127;
        float v = W_out[k * 64 + n];
        _Float16 hi = (_Float16)v;
        _Float16 lo = (_Float16)(v - (float)hi);
        wb[(size_t)10 * 16384 + e] = hi;
        wb[(size_t)11 * 16384 + e] = lo;
    }
}

// ---------------------------------------------------------------------------
// Split-fp16 MFMA GEMM: C[M,BN] = A1 @ B1 (+ A2 @ B2) (+ bias), K=128, f32 I/O.
// a@b = hi@hi + hi@lo + lo@hi (lo@lo dropped, ~2^-22 rel).
// ---------------------------------------------------------------------------
template <int BN, bool DUAL, bool BIAS>
__global__ __launch_bounds__(256)
void gemm_mfma(const float* __restrict__ A1, const float* __restrict__ A2,
               const _Float16* __restrict__ B1h, const _Float16* __restrict__ B1l,
               const _Float16* __restrict__ B2h, const _Float16* __restrict__ B2l,
               const float* __restrict__ bias, float* __restrict__ C, int M) {
    constexpr int NSRC = DUAL ? 2 : 1;
    constexpr int NT = BN / 32;
    constexpr int TPW = NT / 2;

    __shared__ __align__(16) char Alds[NSRC * 2 * 64 * 256];

    const int tid = threadIdx.x;
    const int w = tid >> 6;
    const int lane = tid & 63;
    const int l31 = lane & 31;
    const int kslot = lane >> 5;
    const int row0 = blockIdx.x * 64;

    for (int s = 0; s < NSRC; s++) {
        const float* A = s ? A2 : A1;
        #pragma unroll
        for (int p = 0; p < 8; p++) {
            int idx = tid + p * 256;
            int row = idx >> 5, k4 = idx & 31;
            float4 v = make_float4(0.f, 0.f, 0.f, 0.f);
            if (row0 + row < M) v = *(const float4*)(A + (size_t)(row0 + row) * KDIM + k4 * 4);
            _Float16 h0 = (_Float16)v.x, h1 = (_Float16)v.y,
                     h2 = (_Float16)v.z, h3 = (_Float16)v.w;
            f16x4 hv = {h0, h1, h2, h3};
            f16x4 lv = {(_Float16)(v.x - (float)h0), (_Float16)(v.y - (float)h1),
                        (_Float16)(v.z - (float)h2), (_Float16)(v.w - (float)h3)};
            int boff = (k4 * 8) ^ ((row & 7) << 4);
            *(f16x4*)(Alds + (s * 2 + 0) * 16384 + row * 256 + boff) = hv;
            *(f16x4*)(Alds + (s * 2 + 1) * 16384 + row * 256 + boff) = lv;
        }
    }
    __syncthreads();

    const int n0 = (BN == 128) ? w * 32 : (w & 1) * 32;
    const int mt0 = (BN == 128) ? 0 : (w >> 1);

    f32x16 acc[TPW];
    #pragma unroll
    for (int t = 0; t < TPW; t++)
        #pragma unroll
        for (int e = 0; e < 16; e++) acc[t][e] = 0.0f;

    for (int s = 0; s < NSRC; s++) {
        const _Float16* Bh = s ? B2h : B1h;
        const _Float16* Bl = s ? B2l : B1l;
        const _Float16* bph = Bh + (size_t)(n0 + l31) * 128 + kslot * 8;
        const _Float16* bpl = Bl + (size_t)(n0 + l31) * 128 + kslot * 8;
        const char* abase = Alds + (size_t)(s * 2) * 16384;
        #pragma unroll
        for (int kb = 0; kb < 8; kb++) {
            f16x8 bh = *(const f16x8*)(bph + kb * 16);
            f16x8 bl = *(const f16x8*)(bpl + kb * 16);
            #pragma unroll
            for (int t = 0; t < TPW; t++) {
                int row = (mt0 + t) * 32 + l31;
                int boff = ((kb * 2 + kslot) * 16) ^ ((row & 7) << 4);
                const char* rp = abase + row * 256 + boff;
                f16x8 ah = *(const f16x8*)(rp);
                f16x8 al = *(const f16x8*)(rp + 16384);
                acc[t] = __builtin_amdgcn_mfma_f32_32x32x16_f16(al, bh, acc[t], 0, 0, 0);
                acc[t] = __builtin_amdgcn_mfma_f32_32x32x16_f16(ah, bl, acc[t], 0, 0, 0);
                acc[t] = __builtin_amdgcn_mfma_f32_32x32x16_f16(ah, bh, acc[t], 0, 0, 0);
            }
        }
    }

    float bv = 0.0f;
    if (BIAS) bv = bias[n0 + l31];
    #pragma unroll
    for (int t = 0; t < TPW; t++) {
        #pragma unroll
        for (int r = 0; r < 16; r++) {
            int row = row0 + (mt0 + t) * 32 + (r & 3) + 8 * (r >> 2) + 4 * kslot;
            if (row < M) C[(size_t)row * BN + n0 + l31] = acc[t][r] + bv;
        }
    }
}

// ---------------------------------------------------------------------------
extern "C" void kernel_launch(void* const* d_in, const int* in_sizes, int n_in,
                              void* d_out, int out_size, void* d_ws, size_t ws_size,
                              hipStream_t stream) {
    const float* x       = (const float*)d_in[0];
    const float* W_in    = (const float*)d_in[1];
    const float* b_in    = (const float*)d_in[2];
    const float* W_self  = (const float*)d_in[3];
    const float* W_neigh = (const float*)d_in[4];
    const float* W_out   = (const float*)d_in[5];
    const float* b_out   = (const float*)d_in[6];
    const int*   eidx    = (const int*)d_in[7];

    const int N = 50000, E = 800000;
    const int* src = eidx;
    const int* dst = eidx + E;

    char* ws = (char*)d_ws;
    float* h   = (float*)(ws);                  // 25.6 MB
    float* hs  = (float*)(ws + 25600000);       // 25.6 MB
    float* agg = (float*)(ws + 51200000);       // 25.6 MB
    int* cnt     = (int*)(ws + 76800000);       // 200 KB
    int* row_ptr = (int*)(ws + 77000000);       // 200 KB
    int* cursor  = (int*)(ws + 77200016);       // 200 KB
    int* col     = (int*)(ws + 77400016);       // 3.2 MB
    _Float16* wb = (_Float16*)(ws + 80600016);  // 384 KB weight slots
    int* bsum    = (int*)(ws + 81000016);       // 1 KB scan block sums

    const _Float16* WinT_h  = wb + (size_t)0 * 16384;
    const _Float16* WinT_l  = wb + (size_t)1 * 16384;
    const _Float16* WoutT_h = wb + (size_t)10 * 16384;
    const _Float16* WoutT_l = wb + (size_t)11 * 16384;

    const int NB = (N + 255) / 256;       // 196 scan blocks
    const int EG = ((E + ECHUNK - 1) / ECHUNK) * 8;  // 2000 xcd-chunked blocks

    hipMemsetAsync(cnt, 0, N * sizeof(int), stream);
    hist_kernel<<<EG, 256, 0, stream>>>(src, cnt, E);
    scan1_kernel<<<NB, 256, 0, stream>>>(cnt, row_ptr, bsum, N);
    scan2_kernel<<<1, 256, 0, stream>>>(bsum, NB);
    scan3_kernel<<<NB, 256, 0, stream>>>(bsum, row_ptr, cursor, N, E);
    scatter_kernel<<<EG, 256, 0, stream>>>(src, dst, cursor, col, E);
    sortrows_kernel<<<(N + 3) / 4, 256, 0, stream>>>(row_ptr, col, N);
    conv_wt_kernel<<<(90112 + 255) / 256, 256, 0, stream>>>(W_in, W_self, W_neigh, W_out, wb);

    const int G = (N + 63) / 64;  // 782

    // h = x @ W_in + b_in
    gemm_mfma<128, false, true><<<G, 256, 0, stream>>>(
        x, nullptr, WinT_h, WinT_l, nullptr, nullptr, b_in, h, N);

    for (int i = 0; i < 2; i++) {
        maxk_kernel<<<(N + 3) / 4, 256, 0, stream>>>(h, hs, N);
        aggregate_kernel<<<(N + 3) / 4, 256, 0, stream>>>(hs, row_ptr, col, agg, N);
        const _Float16* WsT_h = wb + (size_t)(2 + 2 * i) * 16384;
        const _Float16* WsT_l = wb + (size_t)(3 + 2 * i) * 16384;
        const _Float16* WnT_h = wb + (size_t)(6 + 2 * i) * 16384;
        const _Float16* WnT_l = wb + (size_t)(7 + 2 * i) * 16384;
        // h = hs @ W_self[i] + agg @ W_neigh[i]
        gemm_mfma<128, true, false><<<G, 256, 0, stream>>>(
            hs, agg, WsT_h, WsT_l, WnT_h, WnT_l, nullptr, h, N);
    }

    // out = h @ W_out + b_out
    gemm_mfma<64, false, true><<<G, 256, 0, stream>>>(
        h, nullptr, WoutT_h, WoutT_l, nullptr, nullptr, b_out, (float*)d_out, N);
}

// Round 9
// 373.581 us; speedup vs baseline: 8.8760x; 1.0061x over previous
//
#include <hip/hip_runtime.h>

#define KDIM 128

typedef _Float16 f16x8 __attribute__((ext_vector_type(8)));
typedef _Float16 f16x4 __attribute__((ext_vector_type(4)));
typedef float f32x16 __attribute__((ext_vector_type(16)));

// ---------------------------------------------------------------------------
// CSR build. hist/scatter are XCD-chunked: block = (chunk<<3)|r, node-range r
// on (round-robin-dispatched) XCD r -> cnt/cursor atomics and col writes stay
// XCD-L2-local.
// ---------------------------------------------------------------------------
#define NRANGE 6250   // 50000 / 8
#define ECHUNK 3200   // edges per chunk; chunks = ceil(E/3200) = 250

__global__ void hist_kernel(const int* __restrict__ src, int* __restrict__ cnt, int E) {
    const int r = blockIdx.x & 7;
    const int chunk = blockIdx.x >> 3;
    const int lo = r * NRANGE, hi = lo + NRANGE;
    const int base = chunk * ECHUNK;
    const int end = min(base + ECHUNK, E);
    for (int i = base + threadIdx.x; i < end; i += 256) {
        int s = src[i];
        if (s >= lo && s < hi) atomicAdd(&cnt[s], 1);
    }
}

__global__ void scatter_kernel(const int* __restrict__ src, const int* __restrict__ dst,
                               int* cursor, int* __restrict__ col, int E) {
    const int r = blockIdx.x & 7;
    const int chunk = blockIdx.x >> 3;
    const int lo = r * NRANGE, hi = lo + NRANGE;
    const int base = chunk * ECHUNK;
    const int end = min(base + ECHUNK, E);
    for (int i = base + threadIdx.x; i < end; i += 256) {
        int s = src[i];
        if (s >= lo && s < hi) {
            int p = atomicAdd(&cursor[s], 1);
            col[p] = dst[i];
        }
    }
}

// Hierarchical exclusive scan of cnt[0..N) -> row_ptr, cursor (3 kernels).
__global__ void scan1_kernel(const int* __restrict__ cnt, int* __restrict__ row_ptr,
                             int* __restrict__ bsum, int N) {
    __shared__ int ws[4];
    const int t = threadIdx.x;
    const int lane = t & 63, w = t >> 6;
    const int i = blockIdx.x * 256 + t;
    int v = (i < N) ? cnt[i] : 0;
    int x = v;
    #pragma unroll
    for (int off = 1; off < 64; off <<= 1) {
        int u = __shfl_up(x, off);
        if (lane >= off) x += u;
    }
    if (lane == 63) ws[w] = x;
    __syncthreads();
    int wexcl = 0;
    #pragma unroll
    for (int k = 0; k < 4; k++) wexcl += (k < w) ? ws[k] : 0;
    if (i < N) row_ptr[i] = wexcl + x - v;      // block-local exclusive
    if (t == 255) bsum[blockIdx.x] = wexcl + x; // block total
}

__global__ void scan2_kernel(int* __restrict__ bsum, int NB) {
    __shared__ int ws[4];
    const int t = threadIdx.x;
    const int lane = t & 63, w = t >> 6;
    int v = (t < NB) ? bsum[t] : 0;
    int x = v;
    #pragma unroll
    for (int off = 1; off < 64; off <<= 1) {
        int u = __shfl_up(x, off);
        if (lane >= off) x += u;
    }
    if (lane == 63) ws[w] = x;
    __syncthreads();
    int wexcl = 0;
    #pragma unroll
    for (int k = 0; k < 4; k++) wexcl += (k < w) ? ws[k] : 0;
    if (t < NB) bsum[t] = wexcl + x - v;        // exclusive block offsets
}

__global__ void scan3_kernel(const int* __restrict__ bsum, int* __restrict__ row_ptr,
                             int* __restrict__ cursor, int N, int E) {
    const int i = blockIdx.x * 256 + threadIdx.x;
    if (i < N) {
        int v = row_ptr[i] + bsum[blockIdx.x];
        row_ptr[i] = v;
        cursor[i] = v;
    }
    if (i == 0) row_ptr[N] = E;
}

// Sort each CSR row's col values ascending -> deterministic summation order.
__global__ void sortrows_kernel(const int* __restrict__ row_ptr, int* __restrict__ col, int M) {
    int wid = (blockIdx.x * blockDim.x + threadIdx.x) >> 6;
    int lane = threadIdx.x & 63;
    if (wid >= M) return;
    int s = row_ptr[wid], e = row_ptr[wid + 1], len = e - s;
    if (len <= 1) return;
    if (len <= 64) {
        int v = (lane < len) ? col[s + lane] : 0x7fffffff;
        #pragma unroll
        for (int k = 2; k <= 64; k <<= 1) {
            #pragma unroll
            for (int j = k >> 1; j > 0; j >>= 1) {
                int o = __shfl_xor(v, j);
                bool dir = ((lane & k) == 0);
                bool smaller = ((lane & j) == 0);
                int mn = min(v, o), mx = max(v, o);
                v = (dir == smaller) ? mn : mx;
            }
        }
        if (lane < len) col[s + lane] = v;
    } else if (lane == 0) {
        for (int a = s + 1; a < e; a++) {
            int key = col[a];
            int b = a - 1;
            while (b >= s && col[b] > key) { col[b + 1] = col[b]; b--; }
            col[b + 1] = key;
        }
    }
}

// ---------------------------------------------------------------------------
// MaxK: keep top-32 of 128 per row (jax.lax.top_k tie-break: lower index wins)
// ---------------------------------------------------------------------------
__global__ void maxk_kernel(const float* __restrict__ h, float* __restrict__ hs, int M) {
    int wid = (blockIdx.x * blockDim.x + threadIdx.x) >> 6;
    int lane = threadIdx.x & 63;
    if (wid >= M) return;
    float2 v = ((const float2*)(h + (size_t)wid * KDIM))[lane];

    unsigned int u0 = __float_as_uint(v.x);
    u0 = (u0 & 0x80000000u) ? ~u0 : (u0 | 0x80000000u);
    unsigned int u1 = __float_as_uint(v.y);
    u1 = (u1 & 0x80000000u) ? ~u1 : (u1 | 0x80000000u);

    unsigned int prefix = 0;
    int remaining = 32;
    #pragma unroll
    for (int b = 31; b >= 0; --b) {
        unsigned int candHi = (prefix >> b) | 1u;
        unsigned long long m0 = __ballot((u0 >> b) == candHi);
        unsigned long long m1 = __ballot((u1 >> b) == candHi);
        int cnt = __popcll(m0) + __popcll(m1);
        if (cnt >= remaining) prefix |= (1u << b);
        else remaining -= cnt;
    }

    unsigned long long e0 = __ballot(u0 == prefix);
    unsigned long long e1 = __ballot(u1 == prefix);
    unsigned long long g0 = __ballot(u0 > prefix);
    unsigned long long g1 = __ballot(u1 > prefix);
    int quota = 32 - (__popcll(g0) + __popcll(g1));
    unsigned long long below = (1ULL << lane) - 1ULL;
    int rank0 = __popcll(e0 & below) + __popcll(e1 & below);
    int rank1 = rank0 + (int)((e0 >> lane) & 1ULL);
    bool k0 = (u0 > prefix) || (((e0 >> lane) & 1ULL) && rank0 < quota);
    bool k1 = (u1 > prefix) || (((e1 >> lane) & 1ULL) && rank1 < quota);

    float2 o;
    o.x = k0 ? v.x : 0.0f;
    o.y = k1 ? v.y : 0.0f;
    ((float2*)(hs + (size_t)wid * KDIM))[lane] = o;
}

// ---------------------------------------------------------------------------
// Aggregation: agg[s] = (sum over CSR row s of hs[col]) / (deg + 1e-6)
// One wave per node; lane owns float2 (64 lanes x 8B = full 512B row).
// 8 independent accumulator chains (edges j = s + c + 8t) -> 8 loads in
// flight sustained; tail (<8) fans out across chains 0..6 (all independent).
// Fixed pairwise combine tree -> deterministic.
// ---------------------------------------------------------------------------
__global__ __launch_bounds__(256)
void aggregate_kernel(const float* __restrict__ hs, const int* __restrict__ row_ptr,
                      const int* __restrict__ col, float* __restrict__ agg, int M) {
    const int lane = threadIdx.x & 63;
    const int wid = (blockIdx.x * blockDim.x + threadIdx.x) >> 6;
    if (wid >= M) return;
    const int s = row_ptr[wid], e = row_ptr[wid + 1];
    const float2* __restrict__ hp = (const float2*)hs;  // row c -> hp[c*64 + lane]

    float2 a0 = make_float2(0.f, 0.f);
    float2 a1 = a0, a2 = a0, a3 = a0, a4 = a0, a5 = a0, a6 = a0, a7 = a0;

    int j = s;
    for (; j + 7 < e; j += 8) {
        int c0 = col[j];     int c1 = col[j + 1];
        int c2 = col[j + 2]; int c3 = col[j + 3];
        int c4 = col[j + 4]; int c5 = col[j + 5];
        int c6 = col[j + 6]; int c7 = col[j + 7];
        float2 v0 = hp[(size_t)c0 * 64 + lane];
        float2 v1 = hp[(size_t)c1 * 64 + lane];
        float2 v2 = hp[(size_t)c2 * 64 + lane];
        float2 v3 = hp[(size_t)c3 * 64 + lane];
        float2 v4 = hp[(size_t)c4 * 64 + lane];
        float2 v5 = hp[(size_t)c5 * 64 + lane];
        float2 v6 = hp[(size_t)c6 * 64 + lane];
        float2 v7 = hp[(size_t)c7 * 64 + lane];
        a0.x += v0.x; a0.y += v0.y;
        a1.x += v1.x; a1.y += v1.y;
        a2.x += v2.x; a2.y += v2.y;
        a3.x += v3.x; a3.y += v3.y;
        a4.x += v4.x; a4.y += v4.y;
        a5.x += v5.x; a5.y += v5.y;
        a6.x += v6.x; a6.y += v6.y;
        a7.x += v7.x; a7.y += v7.y;
    }
    // tail (< 8 edges), independent chains
    if (j < e)     { float2 v = hp[(size_t)col[j]     * 64 + lane]; a0.x += v.x; a0.y += v.y; }
    if (j + 1 < e) { float2 v = hp[(size_t)col[j + 1] * 64 + lane]; a1.x += v.x; a1.y += v.y; }
    if (j + 2 < e) { float2 v = hp[(size_t)col[j + 2] * 64 + lane]; a2.x += v.x; a2.y += v.y; }
    if (j + 3 < e) { float2 v = hp[(size_t)col[j + 3] * 64 + lane]; a3.x += v.x; a3.y += v.y; }
    if (j + 4 < e) { float2 v = hp[(size_t)col[j + 4] * 64 + lane]; a4.x += v.x; a4.y += v.y; }
    if (j + 5 < e) { float2 v = hp[(size_t)col[j + 5] * 64 + lane]; a5.x += v.x; a5.y += v.y; }
    if (j + 6 < e) { float2 v = hp[(size_t)col[j + 6] * 64 + lane]; a6.x += v.x; a6.y += v.y; }

    // fixed combine tree: ((a0+a1)+(a2+a3)) + ((a4+a5)+(a6+a7))
    float2 s01, s23, s45, s67, sA, sB, t;
    s01.x = a0.x + a1.x; s01.y = a0.y + a1.y;
    s23.x = a2.x + a3.x; s23.y = a2.y + a3.y;
    s45.x = a4.x + a5.x; s45.y = a4.y + a5.y;
    s67.x = a6.x + a7.x; s67.y = a6.y + a7.y;
    sA.x = s01.x + s23.x; sA.y = s01.y + s23.y;
    sB.x = s45.x + s67.x; sB.y = s45.y + s67.y;
    t.x = sA.x + sB.x; t.y = sA.y + sB.y;

    float inv = 1.0f / ((float)(e - s) + 1e-6f);
    float2 o;
    o.x = t.x * inv;
    o.y = t.y * inv;
    ((float2*)(agg + (size_t)wid * KDIM))[lane] = o;
}

// ---------------------------------------------------------------------------
// Weight prep: transpose to [n][k] and split f32 -> fp16 (hi, lo).
// ---------------------------------------------------------------------------
__global__ void conv_wt_kernel(const float* __restrict__ W_in,
                               const float* __restrict__ W_self,
                               const float* __restrict__ W_neigh,
                               const float* __restrict__ W_out,
                               _Float16* __restrict__ wb) {
    int t = blockIdx.x * blockDim.x + threadIdx.x;
    if (t < 81920) {
        int m = t >> 14;            // 0..4
        int e = t & 16383;
        int n = e >> 7, k = e & 127;
        const float* S = (m == 0) ? W_in
                       : (m <= 2) ? (W_self + (size_t)(m - 1) * 16384)
                                  : (W_neigh + (size_t)(m - 3) * 16384);
        float v = S[k * 128 + n];
        _Float16 hi = (_Float16)v;
        _Float16 lo = (_Float16)(v - (float)hi);
        int pair = m * 2;
        wb[(size_t)pair * 16384 + n * 128 + k] = hi;
        wb[(size_t)(pair + 1) * 16384 + n * 128 + k] = lo;
    } else if (t < 90112) {
        int e = t - 81920;          // [0, 8192)
        int n = e >> 7, k = e & 127;
        float v = W_out[k * 64 + n];
        _Float16 hi = (_Float16)v;
        _Float16 lo = (_Float16)(v - (float)hi);
        wb[(size_t)10 * 16384 + e] = hi;
        wb[(size_t)11 * 16384 + e] = lo;
    }
}

// ---------------------------------------------------------------------------
// Split-fp16 MFMA GEMM: C[M,BN] = A1 @ B1 (+ A2 @ B2) (+ bias), K=128, f32 I/O.
// a@b = hi@hi + hi@lo + lo@hi (lo@lo dropped, ~2^-22 rel).
// Sources staged SEQUENTIALLY through one 32 KB LDS buffer (stage s -> sync ->
// MFMA s -> sync) so DUAL LDS is 32 KB not 64 KB -> 5 blocks/CU (was 2).
// ---------------------------------------------------------------------------
template <int BN, bool DUAL, bool BIAS>
__global__ __launch_bounds__(256)
void gemm_mfma(const float* __restrict__ A1, const float* __restrict__ A2,
               const _Float16* __restrict__ B1h, const _Float16* __restrict__ B1l,
               const _Float16* __restrict__ B2h, const _Float16* __restrict__ B2l,
               const float* __restrict__ bias, float* __restrict__ C, int M) {
    constexpr int NSRC = DUAL ? 2 : 1;
    constexpr int NT = BN / 32;
    constexpr int TPW = NT / 2;

    __shared__ __align__(16) char Alds[2 * 64 * 256];  // 32 KB: [h/l][row][256B]

    const int tid = threadIdx.x;
    const int w = tid >> 6;
    const int lane = tid & 63;
    const int l31 = lane & 31;
    const int kslot = lane >> 5;
    const int row0 = blockIdx.x * 64;

    const int n0 = (BN == 128) ? w * 32 : (w & 1) * 32;
    const int mt0 = (BN == 128) ? 0 : (w >> 1);

    f32x16 acc[TPW];
    #pragma unroll
    for (int t = 0; t < TPW; t++)
        #pragma unroll
        for (int e = 0; e < 16; e++) acc[t][e] = 0.0f;

    for (int s = 0; s < NSRC; s++) {
        if (s) __syncthreads();   // previous source's MFMA reads done
        // ---- stage A_s: f32 -> (hi,lo) fp16 into swizzled LDS ----
        const float* A = s ? A2 : A1;
        #pragma unroll
        for (int p = 0; p < 8; p++) {
            int idx = tid + p * 256;
            int row = idx >> 5, k4 = idx & 31;
            float4 v = make_float4(0.f, 0.f, 0.f, 0.f);
            if (row0 + row < M) v = *(const float4*)(A + (size_t)(row0 + row) * KDIM + k4 * 4);
            _Float16 h0 = (_Float16)v.x, h1 = (_Float16)v.y,
                     h2 = (_Float16)v.z, h3 = (_Float16)v.w;
            f16x4 hv = {h0, h1, h2, h3};
            f16x4 lv = {(_Float16)(v.x - (float)h0), (_Float16)(v.y - (float)h1),
                        (_Float16)(v.z - (float)h2), (_Float16)(v.w - (float)h3)};
            int boff = (k4 * 8) ^ ((row & 7) << 4);
            *(f16x4*)(Alds + row * 256 + boff) = hv;
            *(f16x4*)(Alds + 16384 + row * 256 + boff) = lv;
        }
        __syncthreads();

        // ---- K-loop ----
        const _Float16* Bh = s ? B2h : B1h;
        const _Float16* Bl = s ? B2l : B1l;
        const _Float16* bph = Bh + (size_t)(n0 + l31) * 128 + kslot * 8;
        const _Float16* bpl = Bl + (size_t)(n0 + l31) * 128 + kslot * 8;
        #pragma unroll
        for (int kb = 0; kb < 8; kb++) {
            f16x8 bh = *(const f16x8*)(bph + kb * 16);
            f16x8 bl = *(const f16x8*)(bpl + kb * 16);
            #pragma unroll
            for (int t = 0; t < TPW; t++) {
                int row = (mt0 + t) * 32 + l31;
                int boff = ((kb * 2 + kslot) * 16) ^ ((row & 7) << 4);
                const char* rp = Alds + row * 256 + boff;
                f16x8 ah = *(const f16x8*)(rp);
                f16x8 al = *(const f16x8*)(rp + 16384);
                acc[t] = __builtin_amdgcn_mfma_f32_32x32x16_f16(al, bh, acc[t], 0, 0, 0);
                acc[t] = __builtin_amdgcn_mfma_f32_32x32x16_f16(ah, bl, acc[t], 0, 0, 0);
                acc[t] = __builtin_amdgcn_mfma_f32_32x32x16_f16(ah, bh, acc[t], 0, 0, 0);
            }
        }
    }

    float bv = 0.0f;
    if (BIAS) bv = bias[n0 + l31];
    #pragma unroll
    for (int t = 0; t < TPW; t++) {
        #pragma unroll
        for (int r = 0; r < 16; r++) {
            int row = row0 + (mt0 + t) * 32 + (r & 3) + 8 * (r >> 2) + 4 * kslot;
            if (row < M) C[(size_t)row * BN + n0 + l31] = acc[t][r] + bv;
        }
    }
}

// ---------------------------------------------------------------------------
extern "C" void kernel_launch(void* const* d_in, const int* in_sizes, int n_in,
                              void* d_out, int out_size, void* d_ws, size_t ws_size,
                              hipStream_t stream) {
    const float* x       = (const float*)d_in[0];
    const float* W_in    = (const float*)d_in[1];
    const float* b_in    = (const float*)d_in[2];
    const float* W_self  = (const float*)d_in[3];
    const float* W_neigh = (const float*)d_in[4];
    const float* W_out   = (const float*)d_in[5];
    const float* b_out   = (const float*)d_in[6];
    const int*   eidx    = (const int*)d_in[7];

    const int N = 50000, E = 800000;
    const int* src = eidx;
    const int* dst = eidx + E;

    char* ws = (char*)d_ws;
    float* h   = (float*)(ws);                  // 25.6 MB
    float* hs  = (float*)(ws + 25600000);       // 25.6 MB
    float* agg = (float*)(ws + 51200000);       // 25.6 MB
    int* cnt     = (int*)(ws + 76800000);       // 200 KB
    int* row_ptr = (int*)(ws + 77000000);       // 200 KB
    int* cursor  = (int*)(ws + 77200016);       // 200 KB
    int* col     = (int*)(ws + 77400016);       // 3.2 MB
    _Float16* wb = (_Float16*)(ws + 80600016);  // 384 KB weight slots
    int* bsum    = (int*)(ws + 81000016);       // 1 KB scan block sums

    const _Float16* WinT_h  = wb + (size_t)0 * 16384;
    const _Float16* WinT_l  = wb + (size_t)1 * 16384;
    const _Float16* WoutT_h = wb + (size_t)10 * 16384;
    const _Float16* WoutT_l = wb + (size_t)11 * 16384;

    const int NB = (N + 255) / 256;       // 196 scan blocks
    const int EG = ((E + ECHUNK - 1) / ECHUNK) * 8;  // 2000 xcd-chunked blocks

    hipMemsetAsync(cnt, 0, N * sizeof(int), stream);
    hist_kernel<<<EG, 256, 0, stream>>>(src, cnt, E);
    scan1_kernel<<<NB, 256, 0, stream>>>(cnt, row_ptr, bsum, N);
    scan2_kernel<<<1, 256, 0, stream>>>(bsum, NB);
    scan3_kernel<<<NB, 256, 0, stream>>>(bsum, row_ptr, cursor, N, E);
    scatter_kernel<<<EG, 256, 0, stream>>>(src, dst, cursor, col, E);
    sortrows_kernel<<<(N + 3) / 4, 256, 0, stream>>>(row_ptr, col, N);
    conv_wt_kernel<<<(90112 + 255) / 256, 256, 0, stream>>>(W_in, W_self, W_neigh, W_out, wb);

    const int G = (N + 63) / 64;  // 782

    // h = x @ W_in + b_in
    gemm_mfma<128, false, true><<<G, 256, 0, stream>>>(
        x, nullptr, WinT_h, WinT_l, nullptr, nullptr, b_in, h, N);

    for (int i = 0; i < 2; i++) {
        maxk_kernel<<<(N + 3) / 4, 256, 0, stream>>>(h, hs, N);
        aggregate_kernel<<<(N + 3) / 4, 256, 0, stream>>>(hs, row_ptr, col, agg, N);
        const _Float16* WsT_h = wb + (size_t)(2 + 2 * i) * 16384;
        const _Float16* WsT_l = wb + (size_t)(3 + 2 * i) * 16384;
        const _Float16* WnT_h = wb + (size_t)(6 + 2 * i) * 16384;
        const _Float16* WnT_l = wb + (size_t)(7 + 2 * i) * 16384;
        // h = hs @ W_self[i] + agg @ W_neigh[i]
        gemm_mfma<128, true, false><<<G, 256, 0, stream>>>(
            hs, agg, WsT_h, WsT_l, WnT_h, WnT_l, nullptr, h, N);
    }

    // out = h @ W_out + b_out
    gemm_mfma<64, false, true><<<G, 256, 0, stream>>>(
        h, nullptr, WoutT_h, WoutT_l, nullptr, nullptr, b_out, (float*)d_out, N);
}